// Round 7
// baseline (346.786 us; speedup 1.0000x reference)
//
#include <hip/hip_runtime.h>

// LSTMTrafficPredictor: fused 2-layer LSTM + FC head via MFMA.
// B=2048, T=512, IN=4, H1=64, H2=32, FC=16, OUT=1.
//
// R24 = R21 (263.8us champion) + MFMA chain-split (the ONLY change).
// R22/R23 post-mortem: dup-column swizzle-elimination REGRESSED (272.2 vs
// 263.8): ds_swizzle latency was already hidden at 3 waves/SIMD; the dup
// scheme doubled h/x ds_write traffic and lengthened wave 8's stream
// (barrier straggler). Reverted. Lesson: in-wave latency is cheap here;
// straggler-wave issue is what the barrier propagates.
// R24 change: accumulator chain MF(z0,C=bias)->MF(z1)->MF(z2) is serial
// depth 3 (~90cy MFMA latency) before gates can start. Split into parallel
// chains MF(z0,bias)->MF(z2) || MF(z1,C=0), then one f4 add: depth 2 MFMA
// + add, saving ~20-30cy/body on BOTH wave types for +2 f4 adds/wave (~4cy
// issue - tiny, per the R20 lesson).
// CLOSED AXES (measured): issue-trimming on balanced stream (R19 flat),
// VALU x-fold on L1 waves (R20 +23us), dup-column swizzle removal (R22
// +8us), multi-block/CU (regs; MB=4 doubles wasted MFMA cols), MB=16 (half
// CUs idle), finer wave split, batch-group phase split.
// Structure: BLK=768 (12 waves: 8 L1 + 4 L2), grid=256, bounds(768,3),
// AGPR-pinned frags, unroll-2 ping-pong, 1 barrier/body, exp2-folded
// weights, ds_swizzle xor-8 redistribution, x-stream on wave 0 lanes.
// k-map (K=128): [h1(0..63) | x(64..67) | 0(68..95) | h2(96..127)]
//   L1: 2 tiles/wave w<8 (unit w*8+nt*4+quad), ks {0,1,2}, C-init=bb1 (AGPR)
//   L2: 2 tiles/wave w>=8 (unit (w-8)*8+tt*4+quad), ks {0,1,3}, C-init=bb2
//   z offset(k,n) = (k>>5)*512 + (((k>>3)&3)*16+n)*8 + (k&7); frag read = lane*8.
// ACT job map (both layers): lane(quad,col) -> unit base + (col>>3)*4 + quad,
//   batch col&7; col<8 uses own acc tile0, col>=8 uses swizzle(xor8) tile1.

#define T_LEN 512
#define IN_F  4
#define H1    64
#define H2    32
#define FCN   16
#define MB    8
#define BLK   768
#define NW1   8     // layer-1 waves; waves NW1..11 are layer-2

typedef __attribute__((ext_vector_type(8))) short s8b;  // 8 bf16 = 4 VGPR
typedef __attribute__((ext_vector_type(4))) float f4;   // MFMA acc
typedef __attribute__((ext_vector_type(4))) int   i4;   // 4 dwords (pin unit)

union S8U { s8b v; i4 d; unsigned short u[8]; };
union F4U { f4 v; i4 d; float f[4]; };

// Pin 4 consecutive regs into AGPRs; asm def kills rematerialization.
#define APIN4(x) asm volatile("" : "+a"((x).d))

#define MF(a, b, c) __builtin_amdgcn_mfma_f32_16x16x32_bf16((a), (b), (c), 0, 0, 0)
#define EX2(x) __builtin_amdgcn_exp2f(x)

#define L2E   1.4426950408889634f
#define L2E2  2.885390081777927f   // 2*log2(e)

__device__ __forceinline__ float rcp_(float x) { return __builtin_amdgcn_rcpf(x); }
// tanh(x) via exp2: 1 - 2/(2^(2x*log2e)+1)
__device__ __forceinline__ float tanh_(float x) {
    return 1.0f - 2.0f * rcp_(EX2(x * L2E2) + 1.0f);
}

__device__ __forceinline__ unsigned short bf16_rne(float f) {   // loader only
    unsigned u = __float_as_uint(f);
    u = u + 0x7FFFu + ((u >> 16) & 1u);
    return (unsigned short)(u >> 16);
}
__device__ __forceinline__ unsigned short bf16_cvt(float f) {   // hot path: 1 instr
    unsigned r;
    asm("v_cvt_pk_bf16_f32 %0, %1, %2" : "=v"(r) : "v"(f), "v"(f));
    return (unsigned short)r;
}

// xor-8 lane swizzle of an f4 (4x ds_swizzle_b32, BitMode xor=8)
#define SWZ8(dst, src)                                                          \
    { F4U t_; t_.v = (src);                                                     \
      (dst).d[0] = __builtin_amdgcn_ds_swizzle(t_.d[0], 0x201F);                \
      (dst).d[1] = __builtin_amdgcn_ds_swizzle(t_.d[1], 0x201F);                \
      (dst).d[2] = __builtin_amdgcn_ds_swizzle(t_.d[2], 0x201F);                \
      (dst).d[3] = __builtin_amdgcn_ds_swizzle(t_.d[3], 0x201F); }

// Shared gate math (gates pre-scaled: i,f,o by log2e; g by 2*log2e).
#define GATES_MATH(G_, CREG, HOUT)                                              \
    const float dI = 1.0f + EX2(-(G_)[0]);                                      \
    const float dF = 1.0f + EX2(-(G_)[1]);                                      \
    const float rIF = rcp_(dI * dF);                                            \
    const float I = dF * rIF, F = dI * rIF;                                     \
    const float dG = EX2((G_)[2]) + 1.0f;                                       \
    const float dO = 1.0f + EX2(-(G_)[3]);                                      \
    const float rGO = rcp_(dG * dO);                                            \
    const float Gg = 1.0f - 2.0f * (dO * rGO), O = dG * rGO;                    \
    CREG = fmaf(F, CREG, I * Gg);                                               \
    const float HOUT = O * tanh_(CREG);

// ---- layer-1 body (waves 0..7): 6 MFMA (split chains), swizzle redist,
// ACT1, h1+x store ----
#define L1_BODY(P, NP, LDOK)                                                    \
    {                                                                           \
        float xn = 0.f;                                                         \
        const bool ld_ = (t < MB * IN_F) && (LDOK);                             \
        if (ld_) xn = *xp;                                                      \
        const s8b z0 = *(const s8b*)(&zz[P][0] + 0 * 512 + offF);               \
        const s8b z1 = *(const s8b*)(&zz[P][0] + 1 * 512 + offF);               \
        const s8b z2 = *(const s8b*)(&zz[P][0] + 2 * 512 + offF);               \
        f4 a0 = MF(wf1[0][0].v, z0, bb1[0].v);                                  \
        f4 a1 = MF(wf1[1][0].v, z0, bb1[1].v);                                  \
        f4 p0 = MF(wf1[0][1].v, z1, fz);                                        \
        f4 p1 = MF(wf1[1][1].v, z1, fz);                                        \
        a0 = MF(wf1[0][2].v, z2, a0);                                           \
        a1 = MF(wf1[1][2].v, z2, a1);                                           \
        a0 = a0 + p0;                                                           \
        a1 = a1 + p1;                                                           \
        F4U rsw; SWZ8(rsw, a1)                                                  \
        f4 g_;                                                                  \
        _Pragma("unroll")                                                       \
        for (int j_ = 0; j_ < 4; ++j_) g_[j_] = lowc ? a0[j_] : rsw.f[j_];      \
        GATES_MATH(g_, c1, h_)                                                  \
        zz[NP][offH] = bf16_cvt(h_);                                            \
        if (ld_) zz[NP][1024 + xn_ * 8 + xf_] = bf16_cvt(xn);                   \
        xp += IN_F;                                                             \
    }

// ---- layer-2 body (waves 8..11): 6 MFMA (split chains), swizzle redist,
// ACT2 (lagged step), h2 store ----
#define L2_MFMA(P)                                                              \
    f4 q0, q1;                                                                  \
    {                                                                           \
        const s8b z0 = *(const s8b*)(&zz[P][0] + 0 * 512 + offF);               \
        const s8b z1 = *(const s8b*)(&zz[P][0] + 1 * 512 + offF);               \
        const s8b z3 = *(const s8b*)(&zz[P][0] + 3 * 512 + offF);               \
        q0 = MF(wf2[0][0].v, z0, bb2[0].v);                                     \
        q1 = MF(wf2[1][0].v, z0, bb2[1].v);                                     \
        f4 r0 = MF(wf2[0][1].v, z1, fz);                                        \
        f4 r1 = MF(wf2[1][1].v, z1, fz);                                        \
        q0 = MF(wf2[0][2].v, z3, q0);                                           \
        q1 = MF(wf2[1][2].v, z3, q1);                                           \
        q0 = q0 + r0;                                                           \
        q1 = q1 + r1;                                                           \
    }

#define L2_ACT(NP)                                                              \
    {                                                                           \
        F4U rsw; SWZ8(rsw, q1)                                                  \
        f4 g_;                                                                  \
        _Pragma("unroll")                                                       \
        for (int j_ = 0; j_ < 4; ++j_) g_[j_] = lowc ? q0[j_] : rsw.f[j_];      \
        GATES_MATH(g_, c2, h_)                                                  \
        zz[NP][off2j] = bf16_cvt(h_);                                           \
    }

__global__ __launch_bounds__(BLK, 3)
void lstm_mfma(const float* __restrict__ x,
               const float* __restrict__ Wih1, const float* __restrict__ Whh1,
               const float* __restrict__ bih1, const float* __restrict__ bhh1,
               const float* __restrict__ Wih2, const float* __restrict__ Whh2,
               const float* __restrict__ bih2, const float* __restrict__ bhh2,
               const float* __restrict__ fc1_w, const float* __restrict__ fc1_b,
               const float* __restrict__ fc2_w, const float* __restrict__ fc2_b,
               float* __restrict__ out)
{
    __shared__ __align__(16) unsigned short zz[2][2048];     // 8 KB
    __shared__ __align__(16) float h2f[MB * H2];
    __shared__ __align__(16) float fcs[MB * FCN];

    const int t    = threadIdx.x;
    const int lane = t & 63;
    const int w    = t >> 6;      // wave 0..11
    const int col  = lane & 15;
    const int quad = lane >> 4;
    const int b0   = blockIdx.x * MB;
    const bool lowc = (col < 8);
    const int w2   = (w >= NW1) ? (w - NW1) : 0;   // L2 wave idx (clamped)

    // ---- weight fragments (bf16, exp2-folded: g-gate rows x 2*log2e) ----
    const float wsc = ((col & 3) == 2) ? L2E2 : L2E;
    S8U wf1[2][3];                // layer1: 2 tiles x ks {0,1,2}
    S8U wf2[2][3];                // layer2: 2 tiles x ks {0,1,3}
    #pragma unroll
    for (int nt = 0; nt < 2; ++nt) {
        const int r1u = (col & 3) * 64 + (w < NW1 ? w : 0) * 8 + nt * 4 + (col >> 2);
        #pragma unroll
        for (int ks = 0; ks < 3; ++ks) {
            #pragma unroll
            for (int j = 0; j < 8; ++j) {
                const int k = ks * 32 + quad * 8 + j;
                float wv = 0.f;
                if      (k < H1)           wv = Whh1[r1u * H1 + k];
                else if (k < H1 + IN_F)    wv = Wih1[r1u * IN_F + (k - H1)];
                wf1[nt][ks].u[j] = bf16_rne(wv * wsc);
            }
        }
    }
    #pragma unroll
    for (int tt = 0; tt < 2; ++tt) {
        const int r2 = (col & 3) * 32 + w2 * 8 + tt * 4 + (col >> 2);
        #pragma unroll
        for (int kf = 0; kf < 3; ++kf) {
            #pragma unroll
            for (int j = 0; j < 8; ++j) {
                const int k = ((kf < 2) ? kf * 32 : 96) + quad * 8 + j;
                const float wv = (k < H1) ? Wih2[r2 * H1 + k]
                                          : Whh2[r2 * H2 + (k - 96)];
                wf2[tt][kf].u[j] = bf16_rne(wv * wsc);
            }
        }
    }
    // biases as exact-f32 MFMA C-init (pre-scaled)
    F4U bb1[2], bb2[2];
    #pragma unroll
    for (int j = 0; j < 4; ++j) {
        const float bsc = (j == 2) ? L2E2 : L2E;
        const int u1a = (w < NW1 ? w : 0) * 8 + quad;         // nt=0 unit
        const int u1b = u1a + 4;                              // nt=1 unit
        bb1[0].f[j] = (bih1[j * 64 + u1a] + bhh1[j * 64 + u1a]) * bsc;
        bb1[1].f[j] = (bih1[j * 64 + u1b] + bhh1[j * 64 + u1b]) * bsc;
        const int u2a = w2 * 8 + quad;                        // tt=0 unit
        const int u2b = u2a + 4;                              // tt=1 unit
        bb2[0].f[j] = (bih2[j * 32 + u2a] + bhh2[j * 32 + u2a]) * bsc;
        bb2[1].f[j] = (bih2[j * 32 + u2b] + bhh2[j * 32 + u2b]) * bsc;
    }

    // ---- PIN fragments + biases into AGPRs ----
    #pragma unroll
    for (int nt = 0; nt < 2; ++nt)
        #pragma unroll
        for (int ks = 0; ks < 3; ++ks) { APIN4(wf1[nt][ks]); APIN4(wf2[nt][ks]); }
    APIN4(bb1[0]); APIN4(bb1[1]); APIN4(bb2[0]); APIN4(bb2[1]);

    const f4 fz = {0.f, 0.f, 0.f, 0.f};

    // ---- init LDS: zero z (both buffers) ----
    {
        int* pz = (int*)zz;       // 2*2048 shorts = 2048 ints
        for (int i = t; i < 2048; i += BLK) pz[i] = 0;
    }
    __syncthreads();
    if (t < MB * IN_F) {                    // x(0) at k=64+f: off = 1024 + n*8 + f
        const int n = t >> 2, f = t & 3;
        const float xv = x[(size_t)(b0 + n) * T_LEN * IN_F + f];
        zz[0][1024 + n * 8 + f] = bf16_rne(xv);
    }
    float c1 = 0.f;   // L1 job: unit w*8+(col>>3)*4+quad, batch col&7
    float c2 = 0.f;   // L2 job: unit w2*8+(col>>3)*4+quad, batch col&7

    // store offsets
    const int uH    = w * 8 + ((col >> 3) << 2) + quad;            // L1 (w<8)
    const int nH    = col & 7;
    const int offH  = (uH >> 5) * 512 + (((uH >> 3) & 3) * 16 + nH) * 8 + (uH & 7);
    const int u2j   = w2 * 8 + ((col >> 3) << 2) + quad;           // L2 (w>=8)
    const int off2j = 1536 + (((u2j >> 3) & 3) * 16 + nH) * 8 + (u2j & 7);
    const int offF  = lane * 8;                    // frag read base
    const int xn_   = (t >> 2) & 7, xf_ = t & 3;   // x-prefetch role (t < 32)
    const float* xp = x + (size_t)(b0 + xn_) * T_LEN * IN_F + IN_F + xf_;  // -> x(1)
    __syncthreads();

    // ================= main recurrence: unrolled x2, 1 barrier/body ==========
    #pragma unroll 1
    for (int s2 = 0; s2 < T_LEN / 2; ++s2) {
        // ---------- body A: s = 2*s2 (read zz[0], write zz[1]) ----------
        if (w < NW1) {
            L1_BODY(0, 1, 1)
        } else {
            L2_MFMA(0)
            if (s2 != 0) L2_ACT(1)       // first body: h2(-1) must stay 0
        }
        __syncthreads();
        // ---------- body B: s = 2*s2+1 (read zz[1], write zz[0]) ----------
        if (w < NW1) {
            L1_BODY(1, 0, (s2 != T_LEN / 2 - 1))
        } else {
            L2_MFMA(1)
            L2_ACT(0)
        }
        __syncthreads();
    }

    // ================= epilogue: layer2 step T-1 (zz[0]: h1(511), h2(510)) ====
    if (w >= NW1) {
        L2_MFMA(0)
        {
            F4U rsw; SWZ8(rsw, q1)
            f4 g_;
            #pragma unroll
            for (int j_ = 0; j_ < 4; ++j_) g_[j_] = lowc ? q0[j_] : rsw.f[j_];
            GATES_MATH(g_, c2, h_)
            h2f[nH * H2 + u2j] = h_;
        }
    }
    __syncthreads();

    // ================= FC head =================
    if (t < MB * FCN) {
        const int b = t >> 4, j = t & 15;
        float s1 = fc1_b[j];
        #pragma unroll
        for (int k = 0; k < H2; ++k)
            s1 = fmaf(fc1_w[j * H2 + k], h2f[b * H2 + k], s1);
        fcs[b * FCN + j] = fmaxf(s1, 0.f);
    }
    __syncthreads();
    if (t < MB) {
        float s2v = fc2_b[0];
        #pragma unroll
        for (int j = 0; j < FCN; ++j)
            s2v = fmaf(fc2_w[j], fcs[t * FCN + j], s2v);
        out[b0 + t] = s2v;
    }
}

extern "C" void kernel_launch(void* const* d_in, const int* in_sizes, int n_in,
                              void* d_out, int out_size, void* d_ws, size_t ws_size,
                              hipStream_t stream) {
    const float* x     = (const float*)d_in[0];
    const float* Wih1  = (const float*)d_in[1];
    const float* Whh1  = (const float*)d_in[2];
    const float* bih1  = (const float*)d_in[3];
    const float* bhh1  = (const float*)d_in[4];
    const float* Wih2  = (const float*)d_in[5];
    const float* Whh2  = (const float*)d_in[6];
    const float* bih2  = (const float*)d_in[7];
    const float* bhh2  = (const float*)d_in[8];
    const float* fc1_w = (const float*)d_in[9];
    const float* fc1_b = (const float*)d_in[10];
    const float* fc2_w = (const float*)d_in[11];
    const float* fc2_b = (const float*)d_in[12];
    float* out = (float*)d_out;

    const int n_batch = 2048;
    dim3 grid(n_batch / MB), block(BLK);
    lstm_mfma<<<grid, block, 0, stream>>>(x, Wih1, Whh1, bih1, bhh1,
                                          Wih2, Whh2, bih2, bhh2,
                                          fc1_w, fc1_b, fc2_w, fc2_b, out);
}

// Round 8
// 303.257 us; speedup vs baseline: 1.1435x; 1.1435x over previous
//
#include <hip/hip_runtime.h>

// LSTMTrafficPredictor: fused 2-layer LSTM + FC head via MFMA.
// B=2048, T=512, IN=4, H1=64, H2=32, FC=16, OUT=1.
//
// R25 = R21 champion (263.8us) + x-prefetch pipelined 2 bodies deep (ONLY
// change). R24 post-mortem: MFMA chain-split REGRESSED 263.8->305.6 (+16%):
// C=0 split chains added 2 live acc pairs (+4 VGPR) and adds that the
// scheduler serialized worse than the depth-3 chain. Ledger: R19 trim flat,
// R20 add -6%, R22 dup-cols -3%, R24 split -16% -> R21 is a tight
// issue/latency balance point; only structural changes win.
// R25 theory: x is STREAMED (each element read once) -> *xp is an HBM-miss
// load (~900cy). R21 issues it at body start and consumes (cvt+store) at
// body END of the SAME body: hiding window ~600cy < 900cy -> wave 0 stalls
// on vmcnt every body and the barrier propagates the straggle to all 12
// waves. Fix: load x(s+3) in body s, store the value loaded 2 bodies ago
// (window ~1500cy >> 900). +2 VGPR, same instruction count, identical
// arithmetic (absmax must stay exactly 1.2207e-4).
// CLOSED AXES (measured): issue-trimming on balanced stream (R19 flat),
// VALU x-fold on L1 waves (R20 +23us), dup-column swizzle removal (R22
// +8us), MFMA chain-split (R24 +42us), multi-block/CU (regs; MB=4 doubles
// wasted MFMA cols), MB=16 (half CUs idle), finer wave split, batch-group
// phase split, cross-wave ACT2 redistribution (R16).
// Structure: BLK=768 (12 waves: 8 L1 + 4 L2), grid=256, bounds(768,3),
// AGPR-pinned frags, unroll-2 ping-pong, 1 barrier/body, exp2-folded
// weights, ds_swizzle xor-8 redistribution, x-stream on wave 0 lanes.
// k-map (K=128): [h1(0..63) | x(64..67) | 0(68..95) | h2(96..127)]
//   L1: 2 tiles/wave w<8 (unit w*8+nt*4+quad), ks {0,1,2}, C-init=bb1 (AGPR)
//   L2: 2 tiles/wave w>=8 (unit (w-8)*8+tt*4+quad), ks {0,1,3}, C-init=bb2
//   z offset(k,n) = (k>>5)*512 + (((k>>3)&3)*16+n)*8 + (k&7); frag read = lane*8.
// ACT job map (both layers): lane(quad,col) -> unit base + (col>>3)*4 + quad,
//   batch col&7; col<8 uses own acc tile0, col>=8 uses swizzle(xor8) tile1.

#define T_LEN 512
#define IN_F  4
#define H1    64
#define H2    32
#define FCN   16
#define MB    8
#define BLK   768
#define NW1   8     // layer-1 waves; waves NW1..11 are layer-2

typedef __attribute__((ext_vector_type(8))) short s8b;  // 8 bf16 = 4 VGPR
typedef __attribute__((ext_vector_type(4))) float f4;   // MFMA acc
typedef __attribute__((ext_vector_type(4))) int   i4;   // 4 dwords (pin unit)

union S8U { s8b v; i4 d; unsigned short u[8]; };
union F4U { f4 v; i4 d; float f[4]; };

// Pin 4 consecutive regs into AGPRs; asm def kills rematerialization.
#define APIN4(x) asm volatile("" : "+a"((x).d))

#define MF(a, b, c) __builtin_amdgcn_mfma_f32_16x16x32_bf16((a), (b), (c), 0, 0, 0)
#define EX2(x) __builtin_amdgcn_exp2f(x)

#define L2E   1.4426950408889634f
#define L2E2  2.885390081777927f   // 2*log2(e)

__device__ __forceinline__ float rcp_(float x) { return __builtin_amdgcn_rcpf(x); }
// tanh(x) via exp2: 1 - 2/(2^(2x*log2e)+1)
__device__ __forceinline__ float tanh_(float x) {
    return 1.0f - 2.0f * rcp_(EX2(x * L2E2) + 1.0f);
}

__device__ __forceinline__ unsigned short bf16_rne(float f) {   // loader only
    unsigned u = __float_as_uint(f);
    u = u + 0x7FFFu + ((u >> 16) & 1u);
    return (unsigned short)(u >> 16);
}
__device__ __forceinline__ unsigned short bf16_cvt(float f) {   // hot path: 1 instr
    unsigned r;
    asm("v_cvt_pk_bf16_f32 %0, %1, %2" : "=v"(r) : "v"(f), "v"(f));
    return (unsigned short)r;
}

// xor-8 lane swizzle of an f4 (4x ds_swizzle_b32, BitMode xor=8)
#define SWZ8(dst, src)                                                          \
    { F4U t_; t_.v = (src);                                                     \
      (dst).d[0] = __builtin_amdgcn_ds_swizzle(t_.d[0], 0x201F);                \
      (dst).d[1] = __builtin_amdgcn_ds_swizzle(t_.d[1], 0x201F);                \
      (dst).d[2] = __builtin_amdgcn_ds_swizzle(t_.d[2], 0x201F);                \
      (dst).d[3] = __builtin_amdgcn_ds_swizzle(t_.d[3], 0x201F); }

// Shared gate math (gates pre-scaled: i,f,o by log2e; g by 2*log2e).
#define GATES_MATH(G_, CREG, HOUT)                                              \
    const float dI = 1.0f + EX2(-(G_)[0]);                                      \
    const float dF = 1.0f + EX2(-(G_)[1]);                                      \
    const float rIF = rcp_(dI * dF);                                            \
    const float I = dF * rIF, F = dI * rIF;                                     \
    const float dG = EX2((G_)[2]) + 1.0f;                                       \
    const float dO = 1.0f + EX2(-(G_)[3]);                                      \
    const float rGO = rcp_(dG * dO);                                            \
    const float Gg = 1.0f - 2.0f * (dO * rGO), O = dG * rGO;                    \
    CREG = fmaf(F, CREG, I * Gg);                                               \
    const float HOUT = O * tanh_(CREG);

// ---- layer-1 core (waves 0..7): 6 MFMA (serial chains), swizzle redist,
// ACT1, h1 store. x staging handled by the caller (prefetch pipeline). ----
#define L1_CORE(P, NP)                                                          \
    {                                                                           \
        const s8b z0 = *(const s8b*)(&zz[P][0] + 0 * 512 + offF);               \
        const s8b z1 = *(const s8b*)(&zz[P][0] + 1 * 512 + offF);               \
        const s8b z2 = *(const s8b*)(&zz[P][0] + 2 * 512 + offF);               \
        f4 a0 = MF(wf1[0][0].v, z0, bb1[0].v);                                  \
        f4 a1 = MF(wf1[1][0].v, z0, bb1[1].v);                                  \
        a0 = MF(wf1[0][1].v, z1, a0);                                           \
        a1 = MF(wf1[1][1].v, z1, a1);                                           \
        a0 = MF(wf1[0][2].v, z2, a0);                                           \
        a1 = MF(wf1[1][2].v, z2, a1);                                           \
        F4U rsw; SWZ8(rsw, a1)                                                  \
        f4 g_;                                                                  \
        _Pragma("unroll")                                                       \
        for (int j_ = 0; j_ < 4; ++j_) g_[j_] = lowc ? a0[j_] : rsw.f[j_];      \
        GATES_MATH(g_, c1, h_)                                                  \
        zz[NP][offH] = bf16_cvt(h_);                                            \
    }

// ---- layer-2 body (waves 8..11): 6 MFMA (serial chains), swizzle redist,
// ACT2 (lagged step), h2 store ----
#define L2_MFMA(P)                                                              \
    f4 q0, q1;                                                                  \
    {                                                                           \
        const s8b z0 = *(const s8b*)(&zz[P][0] + 0 * 512 + offF);               \
        const s8b z1 = *(const s8b*)(&zz[P][0] + 1 * 512 + offF);               \
        const s8b z3 = *(const s8b*)(&zz[P][0] + 3 * 512 + offF);               \
        q0 = MF(wf2[0][0].v, z0, bb2[0].v);                                     \
        q1 = MF(wf2[1][0].v, z0, bb2[1].v);                                     \
        q0 = MF(wf2[0][1].v, z1, q0);                                           \
        q1 = MF(wf2[1][1].v, z1, q1);                                           \
        q0 = MF(wf2[0][2].v, z3, q0);                                           \
        q1 = MF(wf2[1][2].v, z3, q1);                                           \
    }

#define L2_ACT(NP)                                                              \
    {                                                                           \
        F4U rsw; SWZ8(rsw, q1)                                                  \
        f4 g_;                                                                  \
        _Pragma("unroll")                                                       \
        for (int j_ = 0; j_ < 4; ++j_) g_[j_] = lowc ? q0[j_] : rsw.f[j_];      \
        GATES_MATH(g_, c2, h_)                                                  \
        zz[NP][off2j] = bf16_cvt(h_);                                           \
    }

__global__ __launch_bounds__(BLK, 3)
void lstm_mfma(const float* __restrict__ x,
               const float* __restrict__ Wih1, const float* __restrict__ Whh1,
               const float* __restrict__ bih1, const float* __restrict__ bhh1,
               const float* __restrict__ Wih2, const float* __restrict__ Whh2,
               const float* __restrict__ bih2, const float* __restrict__ bhh2,
               const float* __restrict__ fc1_w, const float* __restrict__ fc1_b,
               const float* __restrict__ fc2_w, const float* __restrict__ fc2_b,
               float* __restrict__ out)
{
    __shared__ __align__(16) unsigned short zz[2][2048];     // 8 KB
    __shared__ __align__(16) float h2f[MB * H2];
    __shared__ __align__(16) float fcs[MB * FCN];

    const int t    = threadIdx.x;
    const int lane = t & 63;
    const int w    = t >> 6;      // wave 0..11
    const int col  = lane & 15;
    const int quad = lane >> 4;
    const int b0   = blockIdx.x * MB;
    const bool lowc = (col < 8);
    const int w2   = (w >= NW1) ? (w - NW1) : 0;   // L2 wave idx (clamped)

    // ---- weight fragments (bf16, exp2-folded: g-gate rows x 2*log2e) ----
    const float wsc = ((col & 3) == 2) ? L2E2 : L2E;
    S8U wf1[2][3];                // layer1: 2 tiles x ks {0,1,2}
    S8U wf2[2][3];                // layer2: 2 tiles x ks {0,1,3}
    #pragma unroll
    for (int nt = 0; nt < 2; ++nt) {
        const int r1u = (col & 3) * 64 + (w < NW1 ? w : 0) * 8 + nt * 4 + (col >> 2);
        #pragma unroll
        for (int ks = 0; ks < 3; ++ks) {
            #pragma unroll
            for (int j = 0; j < 8; ++j) {
                const int k = ks * 32 + quad * 8 + j;
                float wv = 0.f;
                if      (k < H1)           wv = Whh1[r1u * H1 + k];
                else if (k < H1 + IN_F)    wv = Wih1[r1u * IN_F + (k - H1)];
                wf1[nt][ks].u[j] = bf16_rne(wv * wsc);
            }
        }
    }
    #pragma unroll
    for (int tt = 0; tt < 2; ++tt) {
        const int r2 = (col & 3) * 32 + w2 * 8 + tt * 4 + (col >> 2);
        #pragma unroll
        for (int kf = 0; kf < 3; ++kf) {
            #pragma unroll
            for (int j = 0; j < 8; ++j) {
                const int k = ((kf < 2) ? kf * 32 : 96) + quad * 8 + j;
                const float wv = (k < H1) ? Wih2[r2 * H1 + k]
                                          : Whh2[r2 * H2 + (k - 96)];
                wf2[tt][kf].u[j] = bf16_rne(wv * wsc);
            }
        }
    }
    // biases as exact-f32 MFMA C-init (pre-scaled)
    F4U bb1[2], bb2[2];
    #pragma unroll
    for (int j = 0; j < 4; ++j) {
        const float bsc = (j == 2) ? L2E2 : L2E;
        const int u1a = (w < NW1 ? w : 0) * 8 + quad;         // nt=0 unit
        const int u1b = u1a + 4;                              // nt=1 unit
        bb1[0].f[j] = (bih1[j * 64 + u1a] + bhh1[j * 64 + u1a]) * bsc;
        bb1[1].f[j] = (bih1[j * 64 + u1b] + bhh1[j * 64 + u1b]) * bsc;
        const int u2a = w2 * 8 + quad;                        // tt=0 unit
        const int u2b = u2a + 4;                              // tt=1 unit
        bb2[0].f[j] = (bih2[j * 32 + u2a] + bhh2[j * 32 + u2a]) * bsc;
        bb2[1].f[j] = (bih2[j * 32 + u2b] + bhh2[j * 32 + u2b]) * bsc;
    }

    // ---- PIN fragments + biases into AGPRs ----
    #pragma unroll
    for (int nt = 0; nt < 2; ++nt)
        #pragma unroll
        for (int ks = 0; ks < 3; ++ks) { APIN4(wf1[nt][ks]); APIN4(wf2[nt][ks]); }
    APIN4(bb1[0]); APIN4(bb1[1]); APIN4(bb2[0]); APIN4(bb2[1]);

    // ---- init LDS: zero z (both buffers) ----
    {
        int* pz = (int*)zz;       // 2*2048 shorts = 2048 ints
        for (int i = t; i < 2048; i += BLK) pz[i] = 0;
    }
    __syncthreads();
    if (t < MB * IN_F) {                    // x(0) at k=64+f: off = 1024 + n*8 + f
        const int n = t >> 2, f = t & 3;
        const float xv = x[(size_t)(b0 + n) * T_LEN * IN_F + f];
        zz[0][1024 + n * 8 + f] = bf16_rne(xv);
    }
    float c1 = 0.f;   // L1 job: unit w*8+(col>>3)*4+quad, batch col&7
    float c2 = 0.f;   // L2 job: unit w2*8+(col>>3)*4+quad, batch col&7

    // store offsets
    const int uH    = w * 8 + ((col >> 3) << 2) + quad;            // L1 (w<8)
    const int nH    = col & 7;
    const int offH  = (uH >> 5) * 512 + (((uH >> 3) & 3) * 16 + nH) * 8 + (uH & 7);
    const int u2j   = w2 * 8 + ((col >> 3) << 2) + quad;           // L2 (w>=8)
    const int off2j = 1536 + (((u2j >> 3) & 3) * 16 + nH) * 8 + (u2j & 7);
    const int offF  = lane * 8;                    // frag read base
    const int xn_   = (t >> 2) & 7, xf_ = t & 3;   // x-prefetch role (t < 32)
    const int xoff  = 1024 + xn_ * 8 + xf_;
    const bool xr   = (t < MB * IN_F);
    const float* xp = x + (size_t)(b0 + xn_) * T_LEN * IN_F + IN_F + xf_;  // -> x(1)

    // x prefetch pipeline, depth 2: xv0 = x(s+1) for the NEXT body's store,
    // xv1 one further. Loads land >= 2 bodies before their cvt+store.
    float xv0 = 0.f, xv1 = 0.f;
    if (xr) {
        xv0 = xp[0];          // x(1)
        xv1 = xp[IN_F];       // x(2)
        xp += 2 * IN_F;       // -> x(3)
    }
    __syncthreads();

    // ================= main recurrence: unrolled x2, 1 barrier/body ==========
    #pragma unroll 1
    for (int s2 = 0; s2 < T_LEN / 2; ++s2) {
        // ---------- body A: s = 2*s2 (read zz[0], write zz[1]) ----------
        if (w < NW1) {
            float xnew = 0.f;
            if (xr && s2 < T_LEN / 2 - 1) xnew = xp[0];   // x(2*s2+3)
            L1_CORE(0, 1)
            if (xr) zz[1][xoff] = bf16_cvt(xv0);          // x(2*s2+1), 2-body-old
            xv0 = xv1; xv1 = xnew; xp += IN_F;
        } else {
            L2_MFMA(0)
            if (s2 != 0) L2_ACT(1)       // first body: h2(-1) must stay 0
        }
        __syncthreads();
        // ---------- body B: s = 2*s2+1 (read zz[1], write zz[0]) ----------
        if (w < NW1) {
            float xnew = 0.f;
            if (xr && s2 < T_LEN / 2 - 2) xnew = xp[0];   // x(2*s2+4)
            L1_CORE(1, 0)
            if (xr && s2 != T_LEN / 2 - 1)
                zz[0][xoff] = bf16_cvt(xv0);              // x(2*s2+2)
            xv0 = xv1; xv1 = xnew; xp += IN_F;
        } else {
            L2_MFMA(1)
            L2_ACT(0)
        }
        __syncthreads();
    }

    // ================= epilogue: layer2 step T-1 (zz[0]: h1(511), h2(510)) ====
    if (w >= NW1) {
        L2_MFMA(0)
        {
            F4U rsw; SWZ8(rsw, q1)
            f4 g_;
            #pragma unroll
            for (int j_ = 0; j_ < 4; ++j_) g_[j_] = lowc ? q0[j_] : rsw.f[j_];
            GATES_MATH(g_, c2, h_)
            h2f[nH * H2 + u2j] = h_;
        }
    }
    __syncthreads();

    // ================= FC head =================
    if (t < MB * FCN) {
        const int b = t >> 4, j = t & 15;
        float s1 = fc1_b[j];
        #pragma unroll
        for (int k = 0; k < H2; ++k)
            s1 = fmaf(fc1_w[j * H2 + k], h2f[b * H2 + k], s1);
        fcs[b * FCN + j] = fmaxf(s1, 0.f);
    }
    __syncthreads();
    if (t < MB) {
        float s2v = fc2_b[0];
        #pragma unroll
        for (int j = 0; j < FCN; ++j)
            s2v = fmaf(fc2_w[j], fcs[t * FCN + j], s2v);
        out[b0 + t] = s2v;
    }
}

extern "C" void kernel_launch(void* const* d_in, const int* in_sizes, int n_in,
                              void* d_out, int out_size, void* d_ws, size_t ws_size,
                              hipStream_t stream) {
    const float* x     = (const float*)d_in[0];
    const float* Wih1  = (const float*)d_in[1];
    const float* Whh1  = (const float*)d_in[2];
    const float* bih1  = (const float*)d_in[3];
    const float* bhh1  = (const float*)d_in[4];
    const float* Wih2  = (const float*)d_in[5];
    const float* Whh2  = (const float*)d_in[6];
    const float* bih2  = (const float*)d_in[7];
    const float* bhh2  = (const float*)d_in[8];
    const float* fc1_w = (const float*)d_in[9];
    const float* fc1_b = (const float*)d_in[10];
    const float* fc2_w = (const float*)d_in[11];
    const float* fc2_b = (const float*)d_in[12];
    float* out = (float*)d_out;

    const int n_batch = 2048;
    dim3 grid(n_batch / MB), block(BLK);
    lstm_mfma<<<grid, block, 0, stream>>>(x, Wih1, Whh1, bih1, bhh1,
                                          Wih2, Whh2, bih2, bhh2,
                                          fc1_w, fc1_b, fc2_w, fc2_b, out);
}